// Round 9
// baseline (175.468 us; speedup 1.0000x reference)
//
#include <hip/hip_runtime.h>

#define NS   125      // n_support
#define NW   5        // n_way
#define NQ   2048
#define DD   8192
#define CREG 0.1f
#define PGD_ITERS 10

// ws float offsets
#define OFF_PART  0                    // 64 * 15625 = 1,000,000 floats (partial K)
#define OFF_K     1000000              // 15625 floats
#define OFF_FLAGS 1015632              // 2 u32 flags (zeroed by gram block 0)
#define OFF_QP3   1016000              // 625
#define OFF_W     1017000              // 5*8192

#define NPART     64                   // d-chunks (128 d each)
#define QPW_BLKS  129                  // 1 QP block + 128 W blocks

// ================= K1: gram partials, 192 blocks = 64 d-chunks x 3 quadrants =====
// K is symmetric: compute (0,0),(0,1),(1,1); (1,0) recovered by mirrored reduce.
// s-major LDS [64][132]: float4 stage (coalesced, conflict-free); 4x4 reg tile.
// Block 0 also zeroes the sync flags for the next dispatch (no memset needed).
__global__ __launch_bounds__(256, 2) void gram192(const float* __restrict__ support,
                                                  float* __restrict__ part,
                                                  unsigned int* __restrict__ flags) {
    __shared__ __align__(16) float As[64][132];   // [s-local][d], pitch 132
    __shared__ __align__(16) float Bs[64][132];
    const int tid = threadIdx.x;
    if (blockIdx.x == 0 && tid == 0) { flags[0] = 0u; flags[1] = 0u; }
    const int qsel = blockIdx.x % 3;              // 0:(0,0) 1:(0,1) 2:(1,1)
    const int c    = blockIdx.x / 3;              // d-chunk 0..63
    const int qy = (qsel == 2) ? 1 : 0;
    const int qz = (qsel == 0) ? 0 : 1;
    const int d0 = c * 128;
    const int sy0 = qy * 64, sz0 = qz * 64;

    // stage: 64 rows x 32 float4 per tile; 8 iters x 256 threads
#pragma unroll
    for (int it = 0; it < 8; ++it) {
        int idx = it * 256 + tid;
        int sl = idx >> 5, d4 = idx & 31;
        int sa = sy0 + sl, sb = sz0 + sl;
        float4 va = (sa < NS) ? *(const float4*)&support[(size_t)sa * DD + d0 + d4 * 4]
                              : make_float4(0.f, 0.f, 0.f, 0.f);
        float4 vb = (sb < NS) ? *(const float4*)&support[(size_t)sb * DD + d0 + d4 * 4]
                              : make_float4(0.f, 0.f, 0.f, 0.f);
        *(float4*)&As[sl][d4 * 4] = va;
        *(float4*)&Bs[sl][d4 * 4] = vb;
    }
    __syncthreads();

    const int tx = tid & 15, ty = tid >> 4;       // rows tx+16i, cols ty+16j
    float acc[4][4];
#pragma unroll
    for (int i = 0; i < 4; i++)
#pragma unroll
        for (int j = 0; j < 4; j++) acc[i][j] = 0.f;

#pragma unroll 4
    for (int d4 = 0; d4 < 32; ++d4) {
        float4 a4[4], b4[4];
#pragma unroll
        for (int i = 0; i < 4; i++) a4[i] = *(const float4*)&As[tx + 16 * i][d4 * 4];
#pragma unroll
        for (int j = 0; j < 4; j++) b4[j] = *(const float4*)&Bs[ty + 16 * j][d4 * 4];
#pragma unroll
        for (int i = 0; i < 4; i++)
#pragma unroll
            for (int j = 0; j < 4; j++)
                acc[i][j] += a4[i].x * b4[j].x + a4[i].y * b4[j].y
                           + a4[i].z * b4[j].z + a4[i].w * b4[j].w;
    }

    float* dst = part + (size_t)c * (NS * NS);
#pragma unroll
    for (int i = 0; i < 4; i++) {
        int gi = sy0 + tx + 16 * i;
        if (gi >= NS) continue;
#pragma unroll
        for (int j = 0; j < 4; j++) {
            int gj = sz0 + ty + 16 * j;
            if (gj < NS) dst[gi * NS + gj] = acc[i][j];
        }
    }
}

// ================= K2: fused kreduce + QP(block 0) + W(blocks 1..128) ============
// Phase 1 (all 129 blocks): reduce a K slice (mirror (1,0) from (0,1)), release.
// Block 0: single relaxed spinner -> acquire -> QP (round-4-verified code) ->
//          release flags[1]. Blocks 1..128: pre-stage support slice into LDS
//          (overlaps QP), single relaxed spinner on flags[1] -> acquire -> W slice.
// 129 blocks <= 256 CUs => all resident => waits deadlock-free.
__global__ __launch_bounds__(256) void qpw(const float* __restrict__ part,
                                           const int* __restrict__ labels,
                                           const float* __restrict__ support,
                                           float* __restrict__ Kg,
                                           unsigned int* __restrict__ flags,
                                           float* __restrict__ qp3,
                                           float* __restrict__ W,
                                           float* __restrict__ outNumSv) {
    __shared__ __align__(16) float smem[9920];    // 39.7 KB union (qp | w)
    __shared__ float rsx[2];
    __shared__ int   svc;
    const int tid = threadIdx.x;
    const int bid = blockIdx.x;

    // ---- phase 1: K reduce slice (all blocks), (1,0) mirrored from (0,1) ----
    for (int t = bid * 256 + tid; t < NS * NS; t += QPW_BLKS * 256) {
        int i = t / NS, j = t - i * NS;
        int src = (i >= 64 && j < 64) ? (j * NS + i) : t;
        float s = 0.f;
#pragma unroll 8
        for (int c = 0; c < NPART; ++c) s += part[(size_t)c * (NS * NS) + src];
        Kg[t] = s;
    }
    __syncthreads();   // drain slice stores before signaling
    if (tid == 0)
        __hip_atomic_fetch_add(&flags[0], 1u, __ATOMIC_RELEASE, __HIP_MEMORY_SCOPE_AGENT);

    if (bid == 0) {
        // ================= QP solve =================
        if (tid == 0) {
            while (__hip_atomic_load(&flags[0], __ATOMIC_RELAXED, __HIP_MEMORY_SCOPE_AGENT) < (unsigned)QPW_BLKS)
                __builtin_amdgcn_s_sleep(8);
        }
        __syncthreads();
        (void)__hip_atomic_load(&flags[0], __ATOMIC_ACQUIRE, __HIP_MEMORY_SCOPE_AGENT);  // fresh Kg

        float* red2 = smem;          // [2][3200] : p*3200 + r*25 + w*5 + a
        float* zsw  = smem + 6400;   // [2][4][NW][32] : p*640 + w*160 + a*32 + j
        const int w    = tid >> 6;
        const int lane = tid & 63;
        const int c0   = w * 32;
        const int r0 = lane, r1 = lane + 64;
        float kr0[32], kr1[32];
#pragma unroll
        for (int j = 0; j < 32; ++j) {
            const int col = c0 + j;
            const bool cv = (col < NS);
            kr0[j] = cv ? Kg[col * NS + r0] : 0.f;
            kr1[j] = (cv && r1 < NS) ? Kg[col * NS + r1] : 0.f;
        }
        for (int idx = tid; idx < 2 * 4 * NW * 32; idx += 256) zsw[idx] = 0.f;
        if (tid == 0) svc = 0;
        float rsum0 = 0.f, rsum1 = 0.f;
#pragma unroll
        for (int j = 0; j < 32; ++j) { rsum0 += fabsf(kr0[j]); rsum1 += fabsf(kr1[j]); }
        red2[r0 * 25 + w * 5] = rsum0;
        red2[r1 * 25 + w * 5] = rsum1;
        __syncthreads();
        const int prw = w * 64 + lane;
        if (w < 2) {
            const float* rr = &red2[prw * 25];
            float t = (prw < NS) ? rr[0] + rr[5] + rr[10] + rr[15] : 0.f;
#pragma unroll
            for (int off = 32; off; off >>= 1) t = fmaxf(t, __shfl_xor(t, off));
            if (lane == 0) rsx[w] = t;
        }
        __syncthreads();
        const float eta = 1.9f / (fmaxf(rsx[0], rsx[1]) + 1.0f);  // G = kron(K,I5)+I
        const int pr  = c0 + lane;
        const bool act = (lane < 32) && (pr < NS);
        const int lab = act ? labels[pr] : 0;
        float z[NW] = {0.f, 0.f, 0.f, 0.f, 0.f};

        for (int it = 0; it < PGD_ITERS; ++it) {
            const int p = it & 1, n = p ^ 1;
            float acc0[NW] = {0.f, 0.f, 0.f, 0.f, 0.f};
            float acc1[NW] = {0.f, 0.f, 0.f, 0.f, 0.f};
            const float* zb = zsw + p * 640 + w * 160;
#pragma unroll
            for (int c = 0; c < 8; ++c) {
                float4 z0 = *(const float4*)&zb[0 * 32 + 4 * c];
                float4 z1 = *(const float4*)&zb[1 * 32 + 4 * c];
                float4 z2 = *(const float4*)&zb[2 * 32 + 4 * c];
                float4 z3 = *(const float4*)&zb[3 * 32 + 4 * c];
                float4 z4 = *(const float4*)&zb[4 * 32 + 4 * c];
                const float k00 = kr0[4*c], k01 = kr0[4*c+1], k02 = kr0[4*c+2], k03 = kr0[4*c+3];
                const float k10 = kr1[4*c], k11 = kr1[4*c+1], k12 = kr1[4*c+2], k13 = kr1[4*c+3];
                acc0[0] += k00*z0.x + k01*z0.y + k02*z0.z + k03*z0.w;
                acc0[1] += k00*z1.x + k01*z1.y + k02*z1.z + k03*z1.w;
                acc0[2] += k00*z2.x + k01*z2.y + k02*z2.z + k03*z2.w;
                acc0[3] += k00*z3.x + k01*z3.y + k02*z3.z + k03*z3.w;
                acc0[4] += k00*z4.x + k01*z4.y + k02*z4.z + k03*z4.w;
                acc1[0] += k10*z0.x + k11*z0.y + k12*z0.z + k13*z0.w;
                acc1[1] += k10*z1.x + k11*z1.y + k12*z1.z + k13*z1.w;
                acc1[2] += k10*z2.x + k11*z2.y + k12*z2.z + k13*z2.w;
                acc1[3] += k10*z3.x + k11*z3.y + k12*z3.z + k13*z3.w;
                acc1[4] += k10*z4.x + k11*z4.y + k12*z4.z + k13*z4.w;
            }
            {
                float* b0 = &red2[p * 3200 + r0 * 25 + w * 5];
                b0[0] = acc0[0]; b0[1] = acc0[1]; b0[2] = acc0[2]; b0[3] = acc0[3]; b0[4] = acc0[4];
                float* b1 = &red2[p * 3200 + r1 * 25 + w * 5];
                b1[0] = acc1[0]; b1[1] = acc1[1]; b1[2] = acc1[2]; b1[3] = acc1[3]; b1[4] = acc1[4];
            }
            __syncthreads();                       // the ONLY barrier per iteration
            if (act) {
                const float* rr = &red2[p * 3200 + pr * 25];
                float v[NW], h[NW];
#pragma unroll
                for (int a = 0; a < NW; a++) {
                    float kz = rr[a] + rr[5 + a] + rr[10 + a] + rr[15 + a];
                    float g = kz + z[a] - ((a == lab) ? 1.f : 0.f);   // Gz + e
                    v[a] = z[a] - eta * g;
                    h[a] = (a == lab) ? CREG : 0.f;
                }
                float tau = fmaxf(fmaxf(fmaxf(v[0], v[1]), fmaxf(v[2], v[3])), v[4]);
#pragma unroll
                for (int nn = 0; nn < 7; ++nn) {
                    float g = 0.f, nf = 0.f;
#pragma unroll
                    for (int a = 0; a < NW; a++) {
                        float d = v[a] - tau;
                        bool fr = (d <= h[a]);
                        g += fr ? d : h[a];
                        nf += fr ? 1.f : 0.f;
                    }
                    tau += g / nf;
                }
#pragma unroll
                for (int a = 0; a < NW; a++) {
                    z[a] = fminf(v[a] - tau, h[a]);
                    zsw[n * 640 + w * 160 + a * 32 + lane] = z[a];
                }
            }
        }

        if (act) {
            float m = fmaxf(fmaxf(fmaxf(z[0], z[1]), fmaxf(z[2], z[3])), z[4]);
            if (m > 0.001f) atomicAdd(&svc, 1);
#pragma unroll
            for (int a = 0; a < NW; a++) qp3[pr * NW + a] = z[a];
        }
        __syncthreads();   // drain qp3 stores + svc
        if (tid == 0) {
            *outNumSv = (float)svc;
            __hip_atomic_fetch_add(&flags[1], 1u, __ATOMIC_RELEASE, __HIP_MEMORY_SCOPE_AGENT);
        }
    } else {
        // ================= W slice (blocks 1..128) =================
        float* sup = smem;           // [125*64] = 8000
        float* q3  = smem + 8000;    // [625]
        float* red = smem + 8640;    // [4*64*NW] = 1280
        const int dbase = (bid - 1) * 64;
        // pre-stage support slice into LDS while QP runs (no dependence on flags)
        for (int idx = tid; idx < NS * 64; idx += 256) {
            int s = idx >> 6, dc = idx & 63;
            sup[idx] = support[(size_t)s * DD + dbase + dc];
        }
        if (tid == 0) {
            while (__hip_atomic_load(&flags[1], __ATOMIC_RELAXED, __HIP_MEMORY_SCOPE_AGENT) < 1u)
                __builtin_amdgcn_s_sleep(16);
        }
        __syncthreads();
        (void)__hip_atomic_load(&flags[1], __ATOMIC_ACQUIRE, __HIP_MEMORY_SCOPE_AGENT);  // fresh qp3
        for (int i = tid; i < NS * NW; i += 256) q3[i] = qp3[i];
        __syncthreads();
        const int ld = tid & 63;
        const int sq = tid >> 6;
        const int s0 = sq * 32;
        const int s1 = (sq == 3) ? NS : (s0 + 32);
        float acc[NW] = {0.f, 0.f, 0.f, 0.f, 0.f};
#pragma unroll 4
        for (int s = s0; s < s1; ++s) {
            float sv = sup[s * 64 + ld];
#pragma unroll
            for (int a = 0; a < NW; a++) acc[a] += sv * q3[s * NW + a];
        }
        float* rr = &red[tid * NW];
#pragma unroll
        for (int a = 0; a < NW; a++) rr[a] = acc[a];
        __syncthreads();
        if (sq == 0) {
#pragma unroll
            for (int a = 0; a < NW; a++) {
                float s = red[(0 * 64 + ld) * NW + a] + red[(1 * 64 + ld) * NW + a]
                        + red[(2 * 64 + ld) * NW + a] + red[(3 * 64 + ld) * NW + a];
                W[(size_t)a * DD + dbase + ld] = s;
            }
        }
    }
}

// ================= K3: logits, 8 queries/block — W load amortized over 8 FMAs ====
__global__ __launch_bounds__(256) void logits8(const float* __restrict__ query,
                                               const float* __restrict__ W,
                                               const float* __restrict__ scale,
                                               float* __restrict__ out) {
    __shared__ float red[4][8][NW];
    const int tid = threadIdx.x;
    const int wave = tid >> 6, lane = tid & 63;
    const int q0 = blockIdx.x * 8;
    const int v0 = wave * 512;             // wave's float4 base (2048 floats of d)
    const float4* W4 = (const float4*)W;
    const float4* q4 = (const float4*)query;
    const float sc = scale[0];

    float acc[8][NW];
#pragma unroll
    for (int k = 0; k < 8; k++)
#pragma unroll
        for (int a = 0; a < NW; a++) acc[k][a] = 0.f;

    for (int it = 0; it < 8; ++it) {
        const int dv = v0 + it * 64 + lane;
        float4 qv[8];
#pragma unroll
        for (int k = 0; k < 8; k++) qv[k] = q4[(size_t)(q0 + k) * (DD / 4) + dv];
#pragma unroll
        for (int a = 0; a < NW; a++) {
            float4 wv = W4[a * (DD / 4) + dv];
#pragma unroll
            for (int k = 0; k < 8; k++)
                acc[k][a] += qv[k].x * wv.x + qv[k].y * wv.y
                           + qv[k].z * wv.z + qv[k].w * wv.w;
        }
    }
#pragma unroll
    for (int off = 32; off; off >>= 1) {
#pragma unroll
        for (int k = 0; k < 8; k++)
#pragma unroll
            for (int a = 0; a < NW; a++) acc[k][a] += __shfl_xor(acc[k][a], off);
    }
    if (lane == 0) {
#pragma unroll
        for (int k = 0; k < 8; k++)
#pragma unroll
            for (int a = 0; a < NW; a++) red[wave][k][a] = acc[k][a];
    }
    __syncthreads();
    if (tid < 8 * NW) {
        const int ql = tid / NW, a = tid % NW;
        float s = red[0][ql][a] + red[1][ql][a] + red[2][ql][a] + red[3][ql][a];
        out[(q0 + ql) * NW + a] = sc * s;
    }
}

extern "C" void kernel_launch(void* const* d_in, const int* in_sizes, int n_in,
                              void* d_out, int out_size, void* d_ws, size_t ws_size,
                              hipStream_t stream) {
    const float* query   = (const float*)d_in[0];
    const float* support = (const float*)d_in[1];
    const int*   labels  = (const int*)d_in[2];
    const float* scale   = (const float*)d_in[5];
    float* out = (float*)d_out;
    float* ws  = (float*)d_ws;

    float* part          = ws + OFF_PART;
    float* Kg            = ws + OFF_K;
    unsigned int* flags  = (unsigned int*)(ws + OFF_FLAGS);
    float* qp3           = ws + OFF_QP3;
    float* W             = ws + OFF_W;

    hipLaunchKernelGGL(gram192, dim3(192), dim3(256), 0, stream, support, part, flags);
    hipLaunchKernelGGL(qpw, dim3(QPW_BLKS), dim3(256), 0, stream,
                       part, labels, support, Kg, flags, qp3, W, out + NQ * NW);
    hipLaunchKernelGGL(logits8, dim3(NQ / 8), dim3(256), 0, stream, query, W, scale, out);
}

// Round 10
// 157.216 us; speedup vs baseline: 1.1161x; 1.1161x over previous
//
#include <hip/hip_runtime.h>

#define NS   125      // n_support
#define NW   5        // n_way
#define NQ   2048
#define DD   8192
#define CREG 0.1f
#define PGD_ITERS 10

// ws float offsets
#define OFF_PART  0                    // 64 * 15625 = 1,000,000 floats (partial K)
#define OFF_K     1000000              // 15625 floats
#define OFF_QP3   1016000              // 625
#define OFF_W     1017000              // 5*8192

#define NPART     64                   // d-chunks (128 d each)

// ================= K1: gram partials, 192 blocks = 64 d-chunks x 3 quadrants =====
// K symmetric: compute (0,0),(0,1),(1,1); (1,0) recovered by mirrored reduce.
// s-major LDS [64][132]: float4 stage (coalesced, conflict-free); 4x4 reg tile.
__global__ __launch_bounds__(256, 2) void gram192(const float* __restrict__ support,
                                                  float* __restrict__ part) {
    __shared__ __align__(16) float As[64][132];   // [s-local][d], pitch 132
    __shared__ __align__(16) float Bs[64][132];
    const int tid = threadIdx.x;
    const int qsel = blockIdx.x % 3;              // 0:(0,0) 1:(0,1) 2:(1,1)
    const int c    = blockIdx.x / 3;              // d-chunk 0..63
    const int qy = (qsel == 2) ? 1 : 0;
    const int qz = (qsel == 0) ? 0 : 1;
    const int d0 = c * 128;
    const int sy0 = qy * 64, sz0 = qz * 64;

    // stage: 64 rows x 32 float4 per tile; 8 iters x 256 threads
#pragma unroll
    for (int it = 0; it < 8; ++it) {
        int idx = it * 256 + tid;
        int sl = idx >> 5, d4 = idx & 31;
        int sa = sy0 + sl, sb = sz0 + sl;
        float4 va = (sa < NS) ? *(const float4*)&support[(size_t)sa * DD + d0 + d4 * 4]
                              : make_float4(0.f, 0.f, 0.f, 0.f);
        float4 vb = (sb < NS) ? *(const float4*)&support[(size_t)sb * DD + d0 + d4 * 4]
                              : make_float4(0.f, 0.f, 0.f, 0.f);
        *(float4*)&As[sl][d4 * 4] = va;
        *(float4*)&Bs[sl][d4 * 4] = vb;
    }
    __syncthreads();

    const int tx = tid & 15, ty = tid >> 4;       // rows tx+16i, cols ty+16j
    float acc[4][4];
#pragma unroll
    for (int i = 0; i < 4; i++)
#pragma unroll
        for (int j = 0; j < 4; j++) acc[i][j] = 0.f;

#pragma unroll 4
    for (int d4 = 0; d4 < 32; ++d4) {
        float4 a4[4], b4[4];
#pragma unroll
        for (int i = 0; i < 4; i++) a4[i] = *(const float4*)&As[tx + 16 * i][d4 * 4];
#pragma unroll
        for (int j = 0; j < 4; j++) b4[j] = *(const float4*)&Bs[ty + 16 * j][d4 * 4];
#pragma unroll
        for (int i = 0; i < 4; i++)
#pragma unroll
            for (int j = 0; j < 4; j++)
                acc[i][j] += a4[i].x * b4[j].x + a4[i].y * b4[j].y
                           + a4[i].z * b4[j].z + a4[i].w * b4[j].w;
    }

    float* dst = part + (size_t)c * (NS * NS);
#pragma unroll
    for (int i = 0; i < 4; i++) {
        int gi = sy0 + tx + 16 * i;
        if (gi >= NS) continue;
#pragma unroll
        for (int j = 0; j < 4; j++) {
            int gj = sz0 + ty + 16 * j;
            if (gj < NS) dst[gi * NS + gj] = acc[i][j];
        }
    }
}

// ================= K2: reduce 64 partials -> K, (1,0) mirrored from (0,1) ========
__global__ __launch_bounds__(256) void kreduce(const float* __restrict__ part,
                                               float* __restrict__ Kg) {
    int t = blockIdx.x * 256 + threadIdx.x;
    if (t < NS * NS) {
        int i = t / NS, j = t - i * NS;
        int src = (i >= 64 && j < 64) ? (j * NS + i) : t;   // mirror lower-left
        float s = 0.f;
#pragma unroll 8
        for (int c = 0; c < NPART; ++c) s += part[(size_t)c * (NS * NS) + src];
        Kg[t] = s;
    }
}

// ================= K3: QP solve, 1 block (r8-proven) =============================
__global__ __launch_bounds__(256) void qp_solve(const float* __restrict__ Kg,
                                                const int* __restrict__ labels,
                                                float* __restrict__ qp3,
                                                float* __restrict__ outNumSv) {
    __shared__ float red2[2][128 * 25];             // [parity][row*25 + w*5 + a]
    __shared__ __align__(16) float zsw[2][4][NW][32];
    __shared__ float rsx[2];
    __shared__ int   svc;

    const int tid  = threadIdx.x;
    const int w    = tid >> 6;
    const int lane = tid & 63;
    const int c0   = w * 32;
    const int r0   = lane, r1 = lane + 64;

    float kr0[32], kr1[32];
#pragma unroll
    for (int j = 0; j < 32; ++j) {
        const int col = c0 + j;
        const bool cv = (col < NS);
        kr0[j] = cv ? Kg[col * NS + r0] : 0.f;
        kr1[j] = (cv && r1 < NS) ? Kg[col * NS + r1] : 0.f;
    }
    for (int idx = tid; idx < 2 * 4 * NW * 32; idx += 256) ((float*)zsw)[idx] = 0.f;
    if (tid == 0) svc = 0;
    float rsum0 = 0.f, rsum1 = 0.f;
#pragma unroll
    for (int j = 0; j < 32; ++j) { rsum0 += fabsf(kr0[j]); rsum1 += fabsf(kr1[j]); }
    red2[0][r0 * 25 + w * 5] = rsum0;
    red2[0][r1 * 25 + w * 5] = rsum1;
    __syncthreads();
    const int prw = w * 64 + lane;
    if (w < 2) {
        const float* rr = &red2[0][prw * 25];
        float t = (prw < NS) ? rr[0] + rr[5] + rr[10] + rr[15] : 0.f;
#pragma unroll
        for (int off = 32; off; off >>= 1) t = fmaxf(t, __shfl_xor(t, off));
        if (lane == 0) rsx[w] = t;
    }
    __syncthreads();
    const float eta = 1.9f / (fmaxf(rsx[0], rsx[1]) + 1.0f);  // G = kron(K,I5)+I
    const int pr   = c0 + lane;
    const bool act = (lane < 32) && (pr < NS);
    const int lab  = act ? labels[pr] : 0;
    float z[NW] = {0.f, 0.f, 0.f, 0.f, 0.f};

    for (int it = 0; it < PGD_ITERS; ++it) {
        const int p = it & 1, n = p ^ 1;
        float acc0[NW] = {0.f, 0.f, 0.f, 0.f, 0.f};
        float acc1[NW] = {0.f, 0.f, 0.f, 0.f, 0.f};
#pragma unroll
        for (int c = 0; c < 8; ++c) {
            float4 z0 = *(const float4*)&zsw[p][w][0][4 * c];
            float4 z1 = *(const float4*)&zsw[p][w][1][4 * c];
            float4 z2 = *(const float4*)&zsw[p][w][2][4 * c];
            float4 z3 = *(const float4*)&zsw[p][w][3][4 * c];
            float4 z4 = *(const float4*)&zsw[p][w][4][4 * c];
            const float k00 = kr0[4*c], k01 = kr0[4*c+1], k02 = kr0[4*c+2], k03 = kr0[4*c+3];
            const float k10 = kr1[4*c], k11 = kr1[4*c+1], k12 = kr1[4*c+2], k13 = kr1[4*c+3];
            acc0[0] += k00*z0.x + k01*z0.y + k02*z0.z + k03*z0.w;
            acc0[1] += k00*z1.x + k01*z1.y + k02*z1.z + k03*z1.w;
            acc0[2] += k00*z2.x + k01*z2.y + k02*z2.z + k03*z2.w;
            acc0[3] += k00*z3.x + k01*z3.y + k02*z3.z + k03*z3.w;
            acc0[4] += k00*z4.x + k01*z4.y + k02*z4.z + k03*z4.w;
            acc1[0] += k10*z0.x + k11*z0.y + k12*z0.z + k13*z0.w;
            acc1[1] += k10*z1.x + k11*z1.y + k12*z1.z + k13*z1.w;
            acc1[2] += k10*z2.x + k11*z2.y + k12*z2.z + k13*z2.w;
            acc1[3] += k10*z3.x + k11*z3.y + k12*z3.z + k13*z3.w;
            acc1[4] += k10*z4.x + k11*z4.y + k12*z4.z + k13*z4.w;
        }
        {
            float* b0 = &red2[p][r0 * 25 + w * 5];
            b0[0] = acc0[0]; b0[1] = acc0[1]; b0[2] = acc0[2]; b0[3] = acc0[3]; b0[4] = acc0[4];
            float* b1 = &red2[p][r1 * 25 + w * 5];
            b1[0] = acc1[0]; b1[1] = acc1[1]; b1[2] = acc1[2]; b1[3] = acc1[3]; b1[4] = acc1[4];
        }
        __syncthreads();                       // the ONLY barrier per iteration
        if (act) {
            const float* rr = &red2[p][pr * 25];
            float v[NW], h[NW];
#pragma unroll
            for (int a = 0; a < NW; a++) {
                float kz = rr[a] + rr[5 + a] + rr[10 + a] + rr[15 + a];
                float g = kz + z[a] - ((a == lab) ? 1.f : 0.f);   // Gz + e
                v[a] = z[a] - eta * g;
                h[a] = (a == lab) ? CREG : 0.f;
            }
            float tau = fmaxf(fmaxf(fmaxf(v[0], v[1]), fmaxf(v[2], v[3])), v[4]);
#pragma unroll
            for (int nn = 0; nn < 7; ++nn) {
                float g = 0.f, nf = 0.f;
#pragma unroll
                for (int a = 0; a < NW; a++) {
                    float d = v[a] - tau;
                    bool fr = (d <= h[a]);
                    g += fr ? d : h[a];
                    nf += fr ? 1.f : 0.f;
                }
                tau += g / nf;
            }
#pragma unroll
            for (int a = 0; a < NW; a++) {
                z[a] = fminf(v[a] - tau, h[a]);
                zsw[n][w][a][lane] = z[a];
            }
        }
    }

    if (act) {
        float m = fmaxf(fmaxf(fmaxf(z[0], z[1]), fmaxf(z[2], z[3])), z[4]);
        if (m > 0.001f) atomicAdd(&svc, 1);
#pragma unroll
        for (int a = 0; a < NW; a++) qp3[pr * NW + a] = z[a];
    }
    __syncthreads();
    if (tid == 0) *outNumSv = (float)svc;
}

// ================= K4: W[a][d] = sum_s support[s][d] * qp3[s][a] =================
__global__ __launch_bounds__(256) void w_kernel(const float* __restrict__ support,
                                                const float* __restrict__ qp3,
                                                float* __restrict__ W) {
    __shared__ float q3[NS * NW];
    __shared__ float red[4 * 64 * NW];
    const int tid = threadIdx.x;
    for (int i = tid; i < NS * NW; i += 256) q3[i] = qp3[i];
    __syncthreads();
    const int ld = tid & 63;
    const int sq = tid >> 6;
    const int d  = blockIdx.x * 64 + ld;
    const int s0 = sq * 32;
    const int s1 = (sq == 3) ? NS : (s0 + 32);
    float acc[NW] = {0.f, 0.f, 0.f, 0.f, 0.f};
#pragma unroll 4
    for (int s = s0; s < s1; ++s) {
        float sv = support[(size_t)s * DD + d];
#pragma unroll
        for (int a = 0; a < NW; a++) acc[a] += sv * q3[s * NW + a];
    }
    float* rr = &red[tid * NW];
#pragma unroll
    for (int a = 0; a < NW; a++) rr[a] = acc[a];
    __syncthreads();
    if (sq == 0) {
#pragma unroll
        for (int a = 0; a < NW; a++) {
            float s = red[(0 * 64 + ld) * NW + a] + red[(1 * 64 + ld) * NW + a]
                    + red[(2 * 64 + ld) * NW + a] + red[(3 * 64 + ld) * NW + a];
            W[(size_t)a * DD + d] = s;
        }
    }
}

// ================= K5: logits, 8 q/block, 512 thr (8 waves -> 33% occupancy) =====
// Wave w covers float4 d-range [w*256, w*256+256); 4 iters x 64 lanes.
// One W float4 amortized over 8 query FMAs.
__global__ __launch_bounds__(512) void logits8w(const float* __restrict__ query,
                                                const float* __restrict__ W,
                                                const float* __restrict__ scale,
                                                float* __restrict__ out) {
    __shared__ float red[8][8][NW];
    const int tid = threadIdx.x;
    const int wave = tid >> 6, lane = tid & 63;
    const int q0 = blockIdx.x * 8;
    const int v0 = wave * 256;             // wave's float4 base (1024 floats of d)
    const float4* W4 = (const float4*)W;
    const float4* q4 = (const float4*)query;
    const float sc = scale[0];

    float acc[8][NW];
#pragma unroll
    for (int k = 0; k < 8; k++)
#pragma unroll
        for (int a = 0; a < NW; a++) acc[k][a] = 0.f;

    for (int it = 0; it < 4; ++it) {
        const int dv = v0 + it * 64 + lane;
        float4 qv[8];
#pragma unroll
        for (int k = 0; k < 8; k++) qv[k] = q4[(size_t)(q0 + k) * (DD / 4) + dv];
#pragma unroll
        for (int a = 0; a < NW; a++) {
            float4 wv = W4[a * (DD / 4) + dv];
#pragma unroll
            for (int k = 0; k < 8; k++)
                acc[k][a] += qv[k].x * wv.x + qv[k].y * wv.y
                           + qv[k].z * wv.z + qv[k].w * wv.w;
        }
    }
#pragma unroll
    for (int off = 32; off; off >>= 1) {
#pragma unroll
        for (int k = 0; k < 8; k++)
#pragma unroll
            for (int a = 0; a < NW; a++) acc[k][a] += __shfl_xor(acc[k][a], off);
    }
    if (lane == 0) {
#pragma unroll
        for (int k = 0; k < 8; k++)
#pragma unroll
            for (int a = 0; a < NW; a++) red[wave][k][a] = acc[k][a];
    }
    __syncthreads();
    if (tid < 8 * NW) {
        const int ql = tid / NW, a = tid % NW;
        float s = 0.f;
#pragma unroll
        for (int wv = 0; wv < 8; ++wv) s += red[wv][ql][a];
        out[(q0 + ql) * NW + a] = sc * s;
    }
}

extern "C" void kernel_launch(void* const* d_in, const int* in_sizes, int n_in,
                              void* d_out, int out_size, void* d_ws, size_t ws_size,
                              hipStream_t stream) {
    const float* query   = (const float*)d_in[0];
    const float* support = (const float*)d_in[1];
    const int*   labels  = (const int*)d_in[2];
    const float* scale   = (const float*)d_in[5];
    float* out = (float*)d_out;
    float* ws  = (float*)d_ws;

    float* part = ws + OFF_PART;
    float* Kg   = ws + OFF_K;
    float* qp3  = ws + OFF_QP3;
    float* W    = ws + OFF_W;

    hipLaunchKernelGGL(gram192, dim3(192), dim3(256), 0, stream, support, part);
    hipLaunchKernelGGL(kreduce, dim3((NS * NS + 255) / 256), dim3(256), 0, stream, part, Kg);
    hipLaunchKernelGGL(qp_solve, dim3(1), dim3(256), 0, stream, Kg, labels, qp3, out + NQ * NW);
    hipLaunchKernelGGL(w_kernel, dim3(DD / 64), dim3(256), 0, stream, support, qp3, W);
    hipLaunchKernelGGL(logits8w, dim3(NQ / 8), dim3(512), 0, stream, query, W, scale, out);
}